// Round 1
// baseline (297.700 us; speedup 1.0000x reference)
//
#include <hip/hip_runtime.h>

#define HW 250   // spatial size
// 8 batches * 32*32 windows = 8192 blocks; 64 tokens/window, C=28, NH=4, HD=7

__global__ __launch_bounds__(256)
void win_attn(const float* __restrict__ x,
              const float* __restrict__ qkv_w,
              const float* __restrict__ qkv_b,
              const float* __restrict__ proj_w,
              const float* __restrict__ proj_b,
              float* __restrict__ out)
{
    __shared__ float xs[64][28];      // x window (zero-padded)
    __shared__ float s_w[84 * 28];    // qkv weight
    __shared__ float s_pw[28 * 28];   // proj weight
    __shared__ float s_qb[84];
    __shared__ float s_pb[28];
    __shared__ float s_q[4][64][8];   // [head][token][dim(7)+pad]
    __shared__ float s_k[4][64][8];
    __shared__ float s_v[4][64][8];
    __shared__ float s_o[64][28];     // attention output (pre-proj)

    const int t   = threadIdx.x;
    const int blk = blockIdx.x;
    const int b   = blk >> 10;        // batch
    const int p   = blk & 1023;       // window id
    const int r0  = (p >> 5) << 3;    // window row base
    const int c0  = (p & 31) << 3;    // window col base

    // ---- stage weights + biases ----
    for (int i = t; i < 84 * 28; i += 256) s_w[i]  = qkv_w[i];
    for (int i = t; i < 28 * 28; i += 256) s_pw[i] = proj_w[i];
    if (t < 84) s_qb[t] = qkv_b[t];
    if (t < 28) s_pb[t] = proj_b[t];

    // ---- stage x window, zero-pad outside [0,250) ----
    for (int i = t; i < 64 * 28; i += 256) {
        const int n  = i / 28, ch = i - n * 28;
        const int r  = r0 + (n >> 3), c = c0 + (n & 7);
        float v = 0.f;
        if (r < HW && c < HW) v = x[((b * HW + r) * HW + c) * 28 + ch];
        xs[n][ch] = v;
    }
    __syncthreads();

    // ---- qkv projection: thread -> (token n, quarter q4) computes 21 channels ----
    {
        const int n = t >> 2, q4 = t & 3;
        float xr[28];
        #pragma unroll
        for (int c4 = 0; c4 < 7; ++c4) {
            const float4 v = *(const float4*)&xs[n][c4 * 4];
            xr[c4*4+0] = v.x; xr[c4*4+1] = v.y; xr[c4*4+2] = v.z; xr[c4*4+3] = v.w;
        }
        #pragma unroll
        for (int j = 0; j < 21; ++j) {
            const int c = q4 * 21 + j;
            const float* wr = &s_w[c * 28];
            float acc = s_qb[c];
            #pragma unroll
            for (int c4 = 0; c4 < 7; ++c4) {
                const float4 w = *(const float4*)&wr[c4 * 4];
                acc += xr[c4*4+0]*w.x + xr[c4*4+1]*w.y + xr[c4*4+2]*w.z + xr[c4*4+3]*w.w;
            }
            const int which = c / 28;
            const int rem   = c - which * 28;
            const int h     = rem / 7;
            const int d     = rem - h * 7;
            float* dst = (which == 0) ? &s_q[h][n][d]
                       : (which == 1) ? &s_k[h][n][d]
                       :                &s_v[h][n][d];
            *dst = acc;
        }
        // zero the pad lane (index 7) so float4 reads are safe (no NaN/Inf)
        const int h2 = t >> 6, n2 = t & 63;
        s_q[h2][n2][7] = 0.f; s_k[h2][n2][7] = 0.f; s_v[h2][n2][7] = 0.f;
    }
    __syncthreads();

    // ---- attention: one thread per (head h, query q); softmax in registers ----
    {
        const int h = t >> 6, q = t & 63;
        const float scale = 0.37796447300922725f; // 7^-0.5
        float4 qa = *(const float4*)&s_q[h][q][0];
        float4 qb4 = *(const float4*)&s_q[h][q][4];
        qa.x *= scale; qa.y *= scale; qa.z *= scale; qa.w *= scale;
        qb4.x *= scale; qb4.y *= scale; qb4.z *= scale; qb4.w = 0.f;

        const int vr = min(8, HW - r0), vc = min(8, HW - c0);
        const bool edge = (vr < 8) || (vc < 8);   // wave-uniform

        float lg[64];
        float mx = -1e30f;
        #pragma unroll
        for (int m = 0; m < 64; ++m) {
            const float4 ka = *(const float4*)&s_k[h][m][0];  // all-lane broadcast
            const float4 kb = *(const float4*)&s_k[h][m][4];
            float acc = qa.x*ka.x + qa.y*ka.y + qa.z*ka.z + qa.w*ka.w
                      + qb4.x*kb.x + qb4.y*kb.y + qb4.z*kb.z;
            if (edge && (((m >> 3) >= vr) || ((m & 7) >= vc))) acc = -1e30f;
            lg[m] = acc;
            mx = fmaxf(mx, acc);
        }
        float sum = 0.f;
        #pragma unroll
        for (int m = 0; m < 64; ++m) {
            const float e = __expf(lg[m] - mx);
            lg[m] = e;
            sum += e;
        }
        const float inv = 1.f / sum;

        float o0=0.f,o1=0.f,o2=0.f,o3=0.f,o4=0.f,o5=0.f,o6=0.f;
        #pragma unroll
        for (int m = 0; m < 64; ++m) {
            const float4 va = *(const float4*)&s_v[h][m][0];  // all-lane broadcast
            const float4 vb = *(const float4*)&s_v[h][m][4];
            const float pm = lg[m];
            o0 += pm*va.x; o1 += pm*va.y; o2 += pm*va.z; o3 += pm*va.w;
            o4 += pm*vb.x; o5 += pm*vb.y; o6 += pm*vb.z;
        }
        float* op = &s_o[q][h * 7];
        op[0]=o0*inv; op[1]=o1*inv; op[2]=o2*inv; op[3]=o3*inv;
        op[4]=o4*inv; op[5]=o5*inv; op[6]=o6*inv;
    }
    __syncthreads();

    // ---- output projection + cropped write ----
    {
        const int n = t >> 2, q4 = t & 3;
        const int r = r0 + (n >> 3), c = c0 + (n & 7);
        if (r < HW && c < HW) {
            float xr[28];
            #pragma unroll
            for (int c4 = 0; c4 < 7; ++c4) {
                const float4 v = *(const float4*)&s_o[n][c4 * 4];
                xr[c4*4+0] = v.x; xr[c4*4+1] = v.y; xr[c4*4+2] = v.z; xr[c4*4+3] = v.w;
            }
            float* dst = &out[((b * HW + r) * HW + c) * 28];
            #pragma unroll
            for (int j = 0; j < 7; ++j) {
                const int co = q4 * 7 + j;
                const float* wr = &s_pw[co * 28];
                float acc = s_pb[co];
                #pragma unroll
                for (int c4 = 0; c4 < 7; ++c4) {
                    const float4 w = *(const float4*)&wr[c4 * 4];
                    acc += xr[c4*4+0]*w.x + xr[c4*4+1]*w.y + xr[c4*4+2]*w.z + xr[c4*4+3]*w.w;
                }
                dst[co] = acc;
            }
        }
    }
}

extern "C" void kernel_launch(void* const* d_in, const int* in_sizes, int n_in,
                              void* d_out, int out_size, void* d_ws, size_t ws_size,
                              hipStream_t stream) {
    const float* x      = (const float*)d_in[0];
    const float* qkv_w  = (const float*)d_in[1];
    const float* qkv_b  = (const float*)d_in[2];
    const float* proj_w = (const float*)d_in[3];
    const float* proj_b = (const float*)d_in[4];
    // inputs 5..18 (DynamicPosBias MLP) provably contribute a per-head constant
    // to pre-softmax logits (PDIM==1 makes every layernorm collapse to its bias),
    // which softmax cancels exactly -> skipped.
    float* out = (float*)d_out;

    dim3 grid(8 * 32 * 32);   // batch * windows
    dim3 block(256);
    hipLaunchKernelGGL(win_attn, grid, block, 0, stream,
                       x, qkv_w, qkv_b, proj_w, proj_b, out);
}

// Round 2
// 157.731 us; speedup vs baseline: 1.8874x; 1.8874x over previous
//
#include <hip/hip_runtime.h>

#define HW 250   // spatial size
// 8 batches * 32*32 windows = 8192 blocks; 64 tokens/window, C=28, NH=4, HD=7

__global__ __launch_bounds__(256, 4)
void win_attn(const float* __restrict__ x,
              const float* __restrict__ qkv_w,
              const float* __restrict__ qkv_b,
              const float* __restrict__ proj_w,
              const float* __restrict__ proj_b,
              float* __restrict__ out)
{
    // LDS plan (37.5 KB -> 4 blocks/CU):
    __shared__ float xs[64 * 32];      // x window; row n, float4 group g stored at (g^(n&7))
    __shared__ float s_w[84 * 28];     // qkv weights; DEAD after P1 -> aliased as s_oT[28*66]
    __shared__ float s_pw[28 * 28];    // proj weights
    __shared__ float s_qb[84];
    __shared__ float s_pb[28];
    __shared__ float s_k[4 * 64 * 8];  // [h][tok][8]; groups swizzled by (tok>>2)&1
    __shared__ float s_v[4 * 64 * 8];
    float* const s_oT = s_w;           // [28][66] transposed attention output (alias)

    const int t   = threadIdx.x;
    const int blk = blockIdx.x;
    const int b   = blk >> 10;
    const int p   = blk & 1023;
    const int r0  = (p >> 5) << 3;
    const int c0  = (p & 31) << 3;

    // ---------------- P0: stage weights + x window ----------------
    for (int i = t; i < 588; i += 256)
        *(float4*)&s_w[i * 4] = *(const float4*)&qkv_w[i * 4];
    for (int i = t; i < 196; i += 256)
        *(float4*)&s_pw[i * 4] = *(const float4*)&proj_w[i * 4];
    if (t < 84) s_qb[t] = qkv_b[t];
    if (t < 28) s_pb[t] = proj_b[t];

    #pragma unroll
    for (int it = 0; it < 2; ++it) {
        const int i = t + it * 256;        // 512 slots, 64 rows x 8 groups (group 7 idle)
        const int n = i >> 3, g = i & 7;
        if (g < 7) {
            const int r = r0 + (n >> 3), c = c0 + (n & 7);
            float4 v = make_float4(0.f, 0.f, 0.f, 0.f);
            if (r < HW && c < HW)
                v = *(const float4*)&x[((b * HW + r) * HW + c) * 28 + g * 4];
            *(float4*)&xs[n * 32 + ((g ^ (n & 7)) << 2)] = v;
        }
    }
    __syncthreads();

    // ---------------- P1: qkv projection ----------------
    // thread t -> token n = t&63, wave w = t>>6. Computes:
    //   - q channels for head w (kept in registers, pre-scaled)
    //   - k or v channels for 2 heads (group w), stored swizzled to LDS
    float qv[7];
    {
        const int n = t & 63, w = t >> 6;
        float xr[28];
        #pragma unroll
        for (int g = 0; g < 7; ++g) {
            const float4 v = *(const float4*)&xs[n * 32 + ((g ^ (n & 7)) << 2)];
            xr[g*4+0] = v.x; xr[g*4+1] = v.y; xr[g*4+2] = v.z; xr[g*4+3] = v.w;
        }
        // k/v: group w -> channels 28 + w*14 .. +13 (wave-uniform weight rows)
        {
            const int cbase = 28 + w * 14;
            float o[14];
            #pragma unroll
            for (int j = 0; j < 14; ++j) {
                const float* wr = &s_w[(cbase + j) * 28];
                float acc = s_qb[cbase + j];
                #pragma unroll
                for (int g = 0; g < 7; ++g) {
                    const float4 ww = *(const float4*)&wr[g * 4];
                    acc += xr[g*4+0]*ww.x + xr[g*4+1]*ww.y + xr[g*4+2]*ww.z + xr[g*4+3]*ww.w;
                }
                o[j] = acc;
            }
            float* buf = (w < 2) ? s_k : s_v;
            const int swz = (n >> 2) & 1;
            #pragma unroll
            for (int hh = 0; hh < 2; ++hh) {
                const int h = ((w & 1) << 1) + hh;
                const float4 lo = make_float4(o[hh*7+0], o[hh*7+1], o[hh*7+2], o[hh*7+3]);
                const float4 hi = make_float4(o[hh*7+4], o[hh*7+5], o[hh*7+6], 0.f);
                *(float4*)&buf[h * 512 + n * 8 + ( swz       << 2)] = lo;  // group 0
                *(float4*)&buf[h * 512 + n * 8 + ((1 ^ swz)  << 2)] = hi;  // group 1
            }
        }
        // q for head w (wave-uniform weight rows); fold in 7^-0.5 * log2(e)
        {
            const float sc = 0.37796447300922725f * 1.4426950408889634f;
            #pragma unroll
            for (int d = 0; d < 7; ++d) {
                const float* wr = &s_w[(w * 7 + d) * 28];
                float acc = s_qb[w * 7 + d];
                #pragma unroll
                for (int g = 0; g < 7; ++g) {
                    const float4 ww = *(const float4*)&wr[g * 4];
                    acc += xr[g*4+0]*ww.x + xr[g*4+1]*ww.y + xr[g*4+2]*ww.z + xr[g*4+3]*ww.w;
                }
                qv[d] = acc * sc;
            }
        }
    }
    __syncthreads();

    // ---------------- P2: attention (thread = head h, query q) ----------------
    {
        const int h = t >> 6, q = t & 63;
        const int vr = min(8, HW - r0), vc = min(8, HW - c0);
        const bool edge = (vr < 8) | (vc < 8);   // wave-uniform

        const float* kb = &s_k[h * 512];
        float lg[64];
        float mx = -1e30f;
        #pragma unroll
        for (int m = 0; m < 64; ++m) {
            const int swz = ((m >> 2) & 1) << 2;
            const float4 ka = *(const float4*)&kb[m * 8 + swz];       // broadcast
            const float4 kc = *(const float4*)&kb[m * 8 + (4 ^ swz)]; // broadcast
            float acc = qv[0]*ka.x + qv[1]*ka.y + qv[2]*ka.z + qv[3]*ka.w
                      + qv[4]*kc.x + qv[5]*kc.y + qv[6]*kc.z;
            if (edge && (((m >> 3) >= vr) || ((m & 7) >= vc))) acc = -1e30f;
            lg[m] = acc;
            mx = fmaxf(mx, acc);
        }
        float sum = 0.f;
        #pragma unroll
        for (int m = 0; m < 64; ++m) {
            const float e = __builtin_amdgcn_exp2f(lg[m] - mx);  // logits pre-scaled by log2e
            lg[m] = e;
            sum += e;
        }
        const float inv = __builtin_amdgcn_rcpf(sum);

        const float* vb = &s_v[h * 512];
        float o0=0.f,o1=0.f,o2=0.f,o3=0.f,o4=0.f,o5=0.f,o6=0.f;
        #pragma unroll
        for (int m = 0; m < 64; ++m) {
            const int swz = ((m >> 2) & 1) << 2;
            const float4 va = *(const float4*)&vb[m * 8 + swz];       // broadcast
            const float4 vc4 = *(const float4*)&vb[m * 8 + (4 ^ swz)];
            const float pm = lg[m];
            o0 += pm*va.x; o1 += pm*va.y; o2 += pm*va.z; o3 += pm*va.w;
            o4 += pm*vc4.x; o5 += pm*vc4.y; o6 += pm*vc4.z;
        }
        // transposed store: s_oT[c][q], c = h*7+d, stride 66 -> 2-way (free)
        float* op = &s_oT[(h * 7) * 66 + q];
        op[0*66]=o0*inv; op[1*66]=o1*inv; op[2*66]=o2*inv; op[3*66]=o3*inv;
        op[4*66]=o4*inv; op[5*66]=o5*inv; op[6*66]=o6*inv;
    }
    __syncthreads();

    // ---------------- P3: output projection + cropped write ----------------
    {
        const int n = t >> 2, q4 = t & 3;
        const int r = r0 + (n >> 3), c = c0 + (n & 7);
        if (r < HW && c < HW) {
            float xr[28];
            #pragma unroll
            for (int cc = 0; cc < 28; ++cc) xr[cc] = s_oT[cc * 66 + n];  // 16 banks, 4-bcast
            float* dst = &out[((b * HW + r) * HW + c) * 28 + q4 * 7];
            #pragma unroll
            for (int j = 0; j < 7; ++j) {
                const int co = q4 * 7 + j;
                const float* wr = &s_pw[co * 28];
                float acc = s_pb[co];
                #pragma unroll
                for (int g = 0; g < 7; ++g) {
                    const float4 w = *(const float4*)&wr[g * 4];
                    acc += xr[g*4+0]*w.x + xr[g*4+1]*w.y + xr[g*4+2]*w.z + xr[g*4+3]*w.w;
                }
                dst[j] = acc;
            }
        }
    }
}

extern "C" void kernel_launch(void* const* d_in, const int* in_sizes, int n_in,
                              void* d_out, int out_size, void* d_ws, size_t ws_size,
                              hipStream_t stream) {
    const float* x      = (const float*)d_in[0];
    const float* qkv_w  = (const float*)d_in[1];
    const float* qkv_b  = (const float*)d_in[2];
    const float* proj_w = (const float*)d_in[3];
    const float* proj_b = (const float*)d_in[4];
    // inputs 5..18 (DynamicPosBias MLP): PDIM==1 makes every layernorm collapse to
    // its bias -> the bias table is a per-head constant -> cancelled by softmax.
    float* out = (float*)d_out;

    dim3 grid(8 * 32 * 32);
    dim3 block(256);
    hipLaunchKernelGGL(win_attn, grid, block, 0, stream,
                       x, qkv_w, qkv_b, proj_w, proj_b, out);
}